// Round 3
// baseline (763.646 us; speedup 1.0000x reference)
//
#include <hip/hip_runtime.h>
#include <math.h>

#define MAXN 0.996f /* (1-PROJ_EPS)/sqrt(c) */
#define AR (1 << 18) /* floats per graph arena (1 MiB) */
#define O_ADJ1 0
#define O_ADJ2 65536
#define O_ADJ3 81920
#define O_U 86016
#define O_T 102400
#define O_DT 118784
#define O_XN 135168
#define O_XN2 143360
#define O_NZW 147456
#define O_NZC 180224
#define O_SROW 212992

__device__ __forceinline__ float wredsum(float v) {
#pragma unroll
  for (int o = 32; o > 0; o >>= 1) v += __shfl_xor(v, o);
  return v;
}

__device__ __forceinline__ float artanh_f(float x) {
  x = fminf(fmaxf(x, -1.0f + 1e-7f), 1.0f - 1e-7f);
  return 0.5f * (log1pf(x) - log1pf(-x));
}

// B-stage hyperbolic chain: expmap0 -> proj -> logmap0 -> relu -> expmap0 -> proj -> logmap0
__device__ __forceinline__ float bchain(float acc) {
  float n0 = sqrtf(wredsum(acc * acc));
  float u0 = fmaxf(n0, 1e-15f);
  float e1 = tanhf(u0) / u0;
  float c1 = fmaxf(e1 * n0, 1e-15f);
  float v = acc * e1;
  if (c1 > MAXN) { v *= MAXN / c1; c1 = MAXN; }
  v *= artanh_f(c1) / c1;
  v = fmaxf(v, 0.f);
  float n2 = sqrtf(wredsum(v * v));
  float u2 = fmaxf(n2, 1e-15f);
  float e2 = tanhf(u2) / u2;
  float c2 = fmaxf(e2 * n2, 1e-15f);
  v *= e2;
  if (c2 > MAXN) { v *= MAXN / c2; c2 = MAXN; }
  v *= artanh_f(c2) / c2;
  return v;
}

// ---------------- Kernel 1: layer-1 HypLinear (wide) + per-row sums ----------------
__global__ __launch_bounds__(256) void k_A1srow(const float* __restrict__ x,
                                                const float* __restrict__ W1,
                                                const float* __restrict__ b1,
                                                float* __restrict__ ws) {
  constexpr int IND = 128, WSTR = 132;
  __shared__ float Wl[64 * WSTR];
  __shared__ float xsh[8 * IND];
  const int tid = threadIdx.x, w = tid >> 6, j = tid & 63;
  const int rowBase = blockIdx.x * 8;
  const int g = rowBase >> 8;
  float* Aa = ws + (size_t)g * AR;
  for (int f = tid; f < 64 * IND; f += 256) { int jj = f >> 7, t = f & 127; Wl[jj * WSTR + t] = W1[f]; }
  for (int f = tid; f < 8 * IND; f += 256) xsh[f] = x[(size_t)rowBase * IND + f];
  __syncthreads();
  // hb = proj(expmap0(b1))
  float bj = b1[j];
  float nb = sqrtf(wredsum(bj * bj));
  float ub = fmaxf(nb, 1e-15f), eb = tanhf(ub) / ub, cb = fmaxf(eb * nb, 1e-15f);
  float hbj = bj * eb * ((cb > MAXN) ? MAXN / cb : 1.0f);
  float y2 = wredsum(hbj * hbj);
  const float4* wrow = (const float4*)(Wl + j * WSTR);
#pragma unroll
  for (int rr = 0; rr < 2; ++rr) {
    const int lr = w * 2 + rr;
    const float* xs = xsh + lr * IND;
    float v0 = xs[j], v1 = xs[64 + j];
    float sr = wredsum(v0 + v1);  // row feature sum (edge weights)
    float a2 = wredsum(v0 * v0 + v1 * v1);
    float nx = sqrtf(a2);
    float un = fmaxf(nx, 1e-15f);
    float s1 = tanhf(un) / un;
    float nv = s1 * nx;
    float nn = fmaxf(nv, 1e-15f);
    float s2 = (nn > MAXN) ? MAXN / nn : 1.0f;
    float alpha = s1 * s2;
    float xnm = fmaxf(fminf(nn, MAXN), 1e-15f);
    const float4* xv4 = (const float4*)xs;
    float y = 0.f;
#pragma unroll
    for (int t4 = 0; t4 < IND / 4; ++t4) {
      float4 w4 = wrow[t4];
      float4 v4 = xv4[t4];
      y += w4.x * v4.x + w4.y * v4.y + w4.z * v4.z + w4.w * v4.w;
    }
    float mxj = alpha * y;
    float mxn = fmaxf(sqrtf(wredsum(mxj * mxj)), 1e-15f);
    float hj = (tanhf(mxn / xnm * artanh_f(xnm)) / mxn) * mxj;
    float hn = fmaxf(sqrtf(wredsum(hj * hj)), 1e-15f);
    if (hn > MAXN) hj *= MAXN / hn;
    float x2v = wredsum(hj * hj);
    float xyv = wredsum(hj * hbj);
    float num = (1.f + 2.f * xyv + y2) * hj + (1.f - x2v) * hbj;
    float den = fmaxf(1.f + 2.f * xyv + x2v * y2, 1e-15f);
    float aj = num / den;
    float an = fmaxf(sqrtf(wredsum(aj * aj)), 1e-15f);
    float pn = an;
    if (an > MAXN) { aj *= MAXN / an; pn = MAXN; }
    const int lrow = (rowBase & 255) + lr;
    if (j == 0) Aa[O_SROW + lrow] = sr;
    Aa[O_U + (size_t)lrow * 64 + j] = (artanh_f(pn) / pn) * aj;
  }
}

// ---------------- device helpers for the mega kernel ----------------
template <int R>
__device__ void csr_build(const float* adjm, int* nzc, float* nzw, int* cntS, float* disS,
                          int w, int j) {
  constexpr int RPW = R / 16;
  unsigned long long below = (j == 0) ? 0ull : ((1ull << j) - 1ull);
#pragma unroll
  for (int i = 0; i < RPW; ++i) {
    int r = w * RPW + i;
    int base = 0;
    float ds = 0.f;
    for (int ch = 0; ch < R / 64; ++ch) {
      int c = ch * 64 + j;
      float v = adjm[(size_t)r * R + c];
      ds += v;
      unsigned long long m = __ballot(v != 0.f);
      int pos = base + __popcll(m & below);
      if (v != 0.f && pos < 128) { nzc[r * 128 + pos] = c; nzw[r * 128 + pos] = v; }
      base += __popcll(m);
    }
    ds = wredsum(ds);
    if (j == 0) {
      cntS[r] = base < 128 ? base : 128;
      disS[r] = (ds > 0.f) ? (1.0f / sqrtf(ds)) : 0.f;
    }
  }
}

template <int ROWS>
__device__ void stageB_sparse(const int* nzc, const float* nzw, const int* cntS,
                              const float* disS, const float* uin, float* tout, float* dtout,
                              int wantDis, int w, int j) {
  constexpr int RPW = ROWS / 16;
#pragma unroll
  for (int i = 0; i < RPW; ++i) {
    int r = w * RPW + i;
    int cnt = cntS[r];
    const int* rc = nzc + r * 128;
    const float* rw = nzw + r * 128;
    float acc = 0.f;
    for (int k = 0; k < cnt; ++k) acc += rw[k] * uin[(size_t)rc[k] * 64 + j];
    float v = bchain(acc);
    tout[(size_t)r * 64 + j] = v;
    if (wantDis) dtout[(size_t)r * 64 + j] = disS[r] * v;
  }
}

template <int ROWS>
__device__ void stageC_sparse(const int* nzc, const float* nzw, const int* cntS,
                              const float* disS, const float* tin, const float* dtin,
                              float* scS, int w, int j) {
  constexpr int RPW = ROWS / 16;
#pragma unroll
  for (int i = 0; i < RPW; ++i) {
    int r = w * RPW + i;
    int cnt = cntS[r];
    const int* rc = nzc + r * 128;
    const float* rw = nzw + r * 128;
    float acc = 0.f;
    for (int k = 0; k < cnt; ++k) acc += rw[k] * dtin[(size_t)rc[k] * 64 + j];
    float d = fabsf(tin[(size_t)r * 64 + j] - disS[r] * acc);
    d = wredsum(d);
    if (j == 0) scS[r] = d;
  }
}

template <int NPGL>
__device__ void stageD(const float* scS, const float* tin, const float* attp, float* xout,
                       float* s1S, float* s2S, int* selS, float* svalS, int tid, int w, int j) {
  constexpr int K = NPGL / 2;
  if (tid < NPGL) {
    float si = scS[tid];
    int rank = 0;
    for (int c = 0; c < NPGL; ++c) { float vv = scS[c]; rank += (vv > si) || (vv == si && c < tid); }
    if (rank < K) { selS[rank] = tid; svalS[rank] = si; }
  }
  __syncthreads();
  constexpr int RPW = K / 16;
  float a1 = attp[j], a2v = attp[64 + j];
#pragma unroll
  for (int i = w * RPW; i < w * RPW + RPW; ++i) {
    int li = selS[i];
    float tv = tanhf(svalS[i]);
    float v = tin[(size_t)li * 64 + j] * tv;
    xout[(size_t)i * 64 + j] = v;
    float sa = wredsum(v * a1);
    float sb = wredsum(v * a2v);
    if (j == 0) { s1S[i] = sa; s2S[i] = sb; }
  }
  __syncthreads();
}

template <int NPGL>
__device__ void stageE(const float* s1S, const float* s2S, const int* selS,
                       const float* adjO, float* adjN, int tid) {
  constexpr int K = NPGL / 2;
  for (int idx = tid; idx < K * K; idx += 1024) {
    int ii = idx / K, jj = idx - ii * K;
    float e = s1S[ii] + s2S[jj];
    adjN[idx] = fmaxf(e, 0.f) + adjO[(size_t)selS[ii] * NPGL + selS[jj]];
  }
}

template <int K>
__device__ void readoutK(const float* xrows, float* xS, int tid) {
  if (tid < 64) {
    float mx = -1e30f, sm = 0.f;
    for (int r = 0; r < K; ++r) { float v = xrows[(size_t)r * 64 + tid]; mx = fmaxf(mx, v); sm += v; }
    xS[tid] = mx;
    xS[64 + tid] = sm * (1.0f / K);
  }
}

// HypLinear (IND=64) with W^T staged in LDS (stride 65: conflict-free scalar reads)
template <int ROWS>
__device__ void stageA64(const float* xin, const float* Wp, const float* bp, float* SM,
                         float* uout, int tid, int w, int j) {
  __syncthreads();
  for (int idx = tid; idx < 64 * 64; idx += 1024) { int jj = idx >> 6, t = idx & 63; SM[t * 65 + jj] = Wp[idx]; }
  __syncthreads();
  float bj = bp[j];
  float nb = sqrtf(wredsum(bj * bj));
  float ub = fmaxf(nb, 1e-15f), eb = tanhf(ub) / ub, cb = fmaxf(eb * nb, 1e-15f);
  float hbj = bj * eb * ((cb > MAXN) ? MAXN / cb : 1.0f);
  float y2 = wredsum(hbj * hbj);
  constexpr int RPW = ROWS / 16;
  float xr[RPW], acc[RPW];
#pragma unroll
  for (int i = 0; i < RPW; ++i) { xr[i] = xin[(size_t)(w * RPW + i) * 64 + j]; acc[i] = 0.f; }
#pragma unroll 8
  for (int t = 0; t < 64; ++t) {
    float wv = SM[t * 65 + j];
#pragma unroll
    for (int i = 0; i < RPW; ++i) acc[i] += __shfl(xr[i], t) * wv;
  }
#pragma unroll
  for (int i = 0; i < RPW; ++i) {
    int r = w * RPW + i;
    float a2 = wredsum(xr[i] * xr[i]);
    float nx = sqrtf(a2);
    float un = fmaxf(nx, 1e-15f);
    float s1 = tanhf(un) / un;
    float nv = s1 * nx;
    float nn = fmaxf(nv, 1e-15f);
    float s2 = (nn > MAXN) ? MAXN / nn : 1.0f;
    float alpha = s1 * s2;
    float xnm = fmaxf(fminf(nn, MAXN), 1e-15f);
    float mxj = alpha * acc[i];
    float mxn = fmaxf(sqrtf(wredsum(mxj * mxj)), 1e-15f);
    float hj = (tanhf(mxn / xnm * artanh_f(xnm)) / mxn) * mxj;
    float hn = fmaxf(sqrtf(wredsum(hj * hj)), 1e-15f);
    if (hn > MAXN) hj *= MAXN / hn;
    float x2v = wredsum(hj * hj);
    float xyv = wredsum(hj * hbj);
    float num = (1.f + 2.f * xyv + y2) * hj + (1.f - x2v) * hbj;
    float den = fmaxf(1.f + 2.f * xyv + x2v * y2, 1e-15f);
    float aj = num / den;
    float an = fmaxf(sqrtf(wredsum(aj * aj)), 1e-15f);
    float pn = an;
    if (an > MAXN) { aj *= MAXN / an; pn = MAXN; }
    uout[(size_t)r * 64 + j] = (artanh_f(pn) / pn) * aj;
  }
  __syncthreads();
}

// ---------------- Kernel 2: everything per-graph (one block per graph) ----------------
__global__ __launch_bounds__(1024) void k_mega(
    const int* __restrict__ er, const int* __restrict__ ec, int EPG,
    const float* __restrict__ W2, const float* __restrict__ b2,
    const float* __restrict__ W3, const float* __restrict__ b3,
    const float* __restrict__ att1, const float* __restrict__ att2,
    const float* __restrict__ lw1, const float* __restrict__ lb1,
    const float* __restrict__ lw2, const float* __restrict__ lb2,
    const float* __restrict__ lw3, const float* __restrict__ lb3,
    float* __restrict__ ws, float* __restrict__ out) {
  const int g = blockIdx.x, tid = threadIdx.x, w = tid >> 6, j = tid & 63;
  float* Aa = ws + (size_t)g * AR;
  float* adj1 = Aa + O_ADJ1;
  float* adj2 = Aa + O_ADJ2;
  float* adj3 = Aa + O_ADJ3;
  float* u = Aa + O_U;
  float* tb = Aa + O_T;
  float* dt = Aa + O_DT;
  float* xn = Aa + O_XN;
  float* xn2 = Aa + O_XN2;
  float* nzw = Aa + O_NZW;
  int* nzc = (int*)(Aa + O_NZC);
  float* srow = Aa + O_SROW;

  __shared__ float SM[64 * 65];
  __shared__ float scS[256];
  __shared__ float disS[256];
  __shared__ int cntS[256];
  __shared__ float svalS[128];
  __shared__ int selS[128];
  __shared__ float s1S[128], s2S[128];
  __shared__ float x1S[128], x2S[128], x3S[128];
  __shared__ float rS[128], h1S[64], h2S[32], zS[8];

  // S0: zero adj1
  {
    float4 z = {0.f, 0.f, 0.f, 0.f};
    float4* a4 = (float4*)adj1;
    for (int i = tid; i < 16384; i += 1024) a4[i] = z;
  }
  __syncthreads();
  // S1: scatter edges (block-local: edges g*EPG..)
  for (int e = tid; e < EPG; e += 1024) {
    int ge = g * EPG + e;
    int r = er[ge] & 255, c = ec[ge] & 255;
    adj1[r * 256 + c] = 0.5f * (srow[r] + srow[c]);
  }
  __syncthreads();
  // CSR of adj1 (~6% dense)
  csr_build<256>(adj1, nzc, nzw, cntS, disS, w, j);
  __syncthreads();
  // B1: HypAgg+HypAct chain (reads u from k_A1srow)
  stageB_sparse<256>(nzc, nzw, cntS, disS, u, tb, dt, 1, w, j);
  __syncthreads();
  // C1: information score
  stageC_sparse<256>(nzc, nzw, cntS, disS, tb, dt, scS, w, j);
  __syncthreads();
  // D1: top-128 + xn + attention projections
  stageD<256>(scS, tb, att1, xn, s1S, s2S, selS, svalS, tid, w, j);
  // E1: structure learning -> adj2 ; readout x1
  stageE<256>(s1S, s2S, selS, adj1, adj2, tid);
  readoutK<128>(xn, x1S, tid);
  __syncthreads();
  // A2: HypLinear layer 2 (128 rows)
  stageA64<128>(xn, W2, b2, SM, u, tid, w, j);
  // CSR of adj2 (~55% dense)
  csr_build<128>(adj2, nzc, nzw, cntS, disS, w, j);
  __syncthreads();
  stageB_sparse<128>(nzc, nzw, cntS, disS, u, tb, dt, 1, w, j);
  __syncthreads();
  stageC_sparse<128>(nzc, nzw, cntS, disS, tb, dt, scS, w, j);
  __syncthreads();
  stageD<128>(scS, tb, att2, xn2, s1S, s2S, selS, svalS, tid, w, j);
  stageE<128>(s1S, s2S, selS, adj2, adj3, tid);
  readoutK<64>(xn2, x2S, tid);
  __syncthreads();
  // A3: HypLinear layer 3 (64 rows)
  stageA64<64>(xn2, W3, b3, SM, u, tid, w, j);
  // B3: dense agg (64x64) + chain
  {
#pragma unroll
    for (int i = 0; i < 4; ++i) {
      int r = w * 4 + i;
      float arow = adj3[(size_t)r * 64 + j];
      float acc = 0.f;
#pragma unroll 16
      for (int c = 0; c < 64; ++c) acc += __shfl(arow, c) * u[(size_t)c * 64 + j];
      tb[(size_t)r * 64 + j] = bchain(acc);
    }
  }
  __syncthreads();
  readoutK<64>(tb, x3S, tid);
  __syncthreads();
  // MLP head + log_softmax
  if (tid < 128) rS[tid] = fmaxf(x1S[tid], 0.f) + fmaxf(x2S[tid], 0.f) + fmaxf(x3S[tid], 0.f);
  __syncthreads();
  if (tid < 64) {
    float a = lb1[tid];
    for (int t = 0; t < 128; ++t) a += rS[t] * lw1[(size_t)tid * 128 + t];
    h1S[tid] = fmaxf(a, 0.f);
  }
  __syncthreads();
  if (tid < 32) {
    float a = lb2[tid];
    for (int t = 0; t < 64; ++t) a += h1S[t] * lw2[(size_t)tid * 64 + t];
    h2S[tid] = fmaxf(a, 0.f);
  }
  __syncthreads();
  if (tid < 6) {
    float a = lb3[tid];
    for (int t = 0; t < 32; ++t) a += h2S[t] * lw3[(size_t)tid * 32 + t];
    zS[tid] = a;
  }
  __syncthreads();
  if (tid < 6) {
    float m = zS[0];
    for (int c = 1; c < 6; ++c) m = fmaxf(m, zS[c]);
    float se = 0.f;
    for (int c = 0; c < 6; ++c) se += expf(zS[c] - m);
    out[(size_t)g * 6 + tid] = zS[tid] - m - logf(se);
  }
}

extern "C" void kernel_launch(void* const* d_in, const int* in_sizes, int n_in,
                              void* d_out, int out_size, void* d_ws, size_t ws_size,
                              hipStream_t stream) {
  const float* x = (const float*)d_in[0];
  const int* ei = (const int*)d_in[1];
  const float* W1 = (const float*)d_in[2];
  const float* b1 = (const float*)d_in[3];
  const float* W2 = (const float*)d_in[4];
  const float* b2 = (const float*)d_in[5];
  const float* W3 = (const float*)d_in[6];
  const float* b3 = (const float*)d_in[7];
  const float* att1 = (const float*)d_in[8];
  const float* att2 = (const float*)d_in[9];
  const float* lw1 = (const float*)d_in[10];
  const float* lb1 = (const float*)d_in[11];
  const float* lw2 = (const float*)d_in[12];
  const float* lb2 = (const float*)d_in[13];
  const float* lw3 = (const float*)d_in[14];
  const float* lb3 = (const float*)d_in[15];
  float* out = (float*)d_out;
  float* ws = (float*)d_ws;
  const int nE = in_sizes[1] / 2;
  const int EPG = nE / 32;

  k_A1srow<<<1024, 256, 0, stream>>>(x, W1, b1, ws);
  k_mega<<<32, 1024, 0, stream>>>(ei, ei + nE, EPG, W2, b2, W3, b3, att1, att2,
                                  lw1, lb1, lw2, lb2, lw3, lb3, ws, out);
}

// Round 4
// 336.559 us; speedup vs baseline: 2.2690x; 2.2690x over previous
//
#include <hip/hip_runtime.h>
#include <math.h>

#define MAXN 0.996f /* (1-PROJ_EPS)/sqrt(c) */

__device__ __forceinline__ float wredsum(float v) {
#pragma unroll
  for (int o = 32; o > 0; o >>= 1) v += __shfl_xor(v, o);
  return v;
}

__device__ __forceinline__ float artanh_f(float x) {
  x = fminf(fmaxf(x, -1.0f + 1e-7f), 1.0f - 1e-7f);
  return 0.5f * (log1pf(x) - log1pf(-x));
}

// B-chain: expmap0 -> proj -> logmap0 -> relu -> expmap0 -> proj -> logmap0
__device__ __forceinline__ float bchain(float acc) {
  float n0 = sqrtf(wredsum(acc * acc));
  float u0 = fmaxf(n0, 1e-15f);
  float e1 = tanhf(u0) / u0;
  float c1 = fmaxf(e1 * n0, 1e-15f);
  float v = acc * e1;
  if (c1 > MAXN) { v *= MAXN / c1; c1 = MAXN; }
  v *= artanh_f(c1) / c1;
  v = fmaxf(v, 0.f);
  float n2 = sqrtf(wredsum(v * v));
  float u2 = fmaxf(n2, 1e-15f);
  float e2 = tanhf(u2) / u2;
  float c2 = fmaxf(e2 * n2, 1e-15f);
  v *= e2;
  if (c2 > MAXN) { v *= MAXN / c2; c2 = MAXN; }
  v *= artanh_f(c2) / c2;
  return v;
}

// A-chain epilogue: given lane's x component (xrv) and raw matvec (accv),
// hyperbolic bias (hbj, y2): mobius_matvec tail + proj + mobius_add + proj + logmap0
__device__ __forceinline__ float achain(float xrv, float accv, float hbj, float y2) {
  float nx = sqrtf(wredsum(xrv * xrv));
  float un = fmaxf(nx, 1e-15f);
  float s1 = tanhf(un) / un;
  float nn = fmaxf(s1 * nx, 1e-15f);
  float s2 = (nn > MAXN) ? MAXN / nn : 1.0f;
  float alpha = s1 * s2;
  float xnm = fmaxf(fminf(nn, MAXN), 1e-15f);
  float mxj = alpha * accv;
  float mxn = fmaxf(sqrtf(wredsum(mxj * mxj)), 1e-15f);
  float hj = (tanhf(mxn / xnm * artanh_f(xnm)) / mxn) * mxj;
  float hn = fmaxf(sqrtf(wredsum(hj * hj)), 1e-15f);
  if (hn > MAXN) hj *= MAXN / hn;
  float x2v = wredsum(hj * hj);
  float xyv = wredsum(hj * hbj);
  float num = (1.f + 2.f * xyv + y2) * hj + (1.f - x2v) * hbj;
  float den = fmaxf(1.f + 2.f * xyv + x2v * y2, 1e-15f);
  float aj = num / den;
  float an = fmaxf(sqrtf(wredsum(aj * aj)), 1e-15f);
  float pn = an;
  if (an > MAXN) { aj *= MAXN / an; pn = MAXN; }
  return (artanh_f(pn) / pn) * aj;
}

__device__ __forceinline__ void biaschain(const float* bp, int j, float& hbj, float& y2) {
  float bj = bp[j];
  float nb = sqrtf(wredsum(bj * bj));
  float ub = fmaxf(nb, 1e-15f), eb = tanhf(ub) / ub, cb = fmaxf(eb * nb, 1e-15f);
  hbj = bj * eb * ((cb > MAXN) ? MAXN / cb : 1.0f);
  y2 = wredsum(hbj * hbj);
}

// ---- K1: zero adj1 slice + layer-1 HypLinear (IND=128) + per-row sums ----
__global__ __launch_bounds__(256) void k_A1(const float* __restrict__ x,
                                            const float* __restrict__ W1,
                                            const float* __restrict__ b1,
                                            float* __restrict__ adj1,
                                            float* __restrict__ u1,
                                            float* __restrict__ srow) {
  constexpr int IND = 128, WSTR = 132;
  __shared__ float Wl[64 * WSTR];
  __shared__ float xsh[8 * IND];
  const int tid = threadIdx.x, w = tid >> 6, j = tid & 63;
  const int rowBase = blockIdx.x * 8;
  // zero this block's 8 KB slice of adj1 (2M floats / 1024 blocks = 2048 floats)
  {
    float4 z = {0.f, 0.f, 0.f, 0.f};
    float4* a4 = (float4*)adj1 + (size_t)blockIdx.x * 512;
    a4[tid] = z;
    a4[tid + 256] = z;
  }
  for (int f = tid; f < 64 * IND; f += 256) { int jj = f >> 7, t = f & 127; Wl[jj * WSTR + t] = W1[f]; }
  for (int f = tid; f < 8 * IND; f += 256) xsh[f] = x[(size_t)rowBase * IND + f];
  __syncthreads();
  float hbj, y2;
  biaschain(b1, j, hbj, y2);
  const float4* wrow = (const float4*)(Wl + j * WSTR);
#pragma unroll
  for (int rr = 0; rr < 2; ++rr) {
    const int lr = w * 2 + rr;
    const float* xs = xsh + lr * IND;
    float v0 = xs[j], v1 = xs[64 + j];
    float sr = wredsum(v0 + v1);
    // expmap0+proj scale, captured inside achain via xrv? IND=128 needs 2 comps:
    float nx = sqrtf(wredsum(v0 * v0 + v1 * v1));
    float un = fmaxf(nx, 1e-15f);
    float s1 = tanhf(un) / un;
    float nn = fmaxf(s1 * nx, 1e-15f);
    float s2 = (nn > MAXN) ? MAXN / nn : 1.0f;
    float alpha = s1 * s2;
    float xnm = fmaxf(fminf(nn, MAXN), 1e-15f);
    const float4* xv4 = (const float4*)xs;
    float y = 0.f;
#pragma unroll
    for (int t4 = 0; t4 < IND / 4; ++t4) {
      float4 w4 = wrow[t4];
      float4 v4 = xv4[t4];
      y += w4.x * v4.x + w4.y * v4.y + w4.z * v4.z + w4.w * v4.w;
    }
    float mxj = alpha * y;
    float mxn = fmaxf(sqrtf(wredsum(mxj * mxj)), 1e-15f);
    float hj = (tanhf(mxn / xnm * artanh_f(xnm)) / mxn) * mxj;
    float hn = fmaxf(sqrtf(wredsum(hj * hj)), 1e-15f);
    if (hn > MAXN) hj *= MAXN / hn;
    float x2v = wredsum(hj * hj);
    float xyv = wredsum(hj * hbj);
    float num = (1.f + 2.f * xyv + y2) * hj + (1.f - x2v) * hbj;
    float den = fmaxf(1.f + 2.f * xyv + x2v * y2, 1e-15f);
    float aj = num / den;
    float an = fmaxf(sqrtf(wredsum(aj * aj)), 1e-15f);
    float pn = an;
    if (an > MAXN) { aj *= MAXN / an; pn = MAXN; }
    const int row = rowBase + lr;
    if (j == 0) srow[row] = sr;
    u1[(size_t)row * 64 + j] = (artanh_f(pn) / pn) * aj;
  }
}

// ---- K2: scatter edges into block-diagonal adj1 ----
__global__ void k_edges(const int* __restrict__ er, const int* __restrict__ ec,
                        const float* __restrict__ srow, float* __restrict__ adj1, int nE) {
  for (int e = blockIdx.x * blockDim.x + threadIdx.x; e < nE; e += gridDim.x * blockDim.x) {
    int r = er[e], c = ec[e];
    adj1[(size_t)r * 256 + (c & 255)] = 0.5f * (srow[r] + srow[c]);
  }
}

// ---- K3/K6: HypAgg+HypAct chain; emits t, dt=dis*t, dis ----
template <int NPGL>
__global__ __launch_bounds__(256) void k_B(const float* __restrict__ adj,
                                           const float* __restrict__ u, float* __restrict__ t,
                                           float* __restrict__ dt, float* __restrict__ dis) {
  __shared__ float adjl[16 * NPGL];
  const int tid = threadIdx.x;
  const int w = tid >> 6, j = tid & 63;
  const int rowBase = blockIdx.x * 16;
  const int g = rowBase / NPGL;
  for (int f = tid; f < 16 * NPGL; f += 256) adjl[f] = adj[(size_t)rowBase * NPGL + f];
  __syncthreads();
  const float* ug = u + (size_t)g * NPGL * 64;
  float acc[4] = {0.f, 0.f, 0.f, 0.f};
  for (int c4 = 0; c4 < NPGL / 4; ++c4) {
    const int c = c4 * 4;
    float u0 = ug[(size_t)(c + 0) * 64 + j];
    float u1v = ug[(size_t)(c + 1) * 64 + j];
    float u2v = ug[(size_t)(c + 2) * 64 + j];
    float u3v = ug[(size_t)(c + 3) * 64 + j];
#pragma unroll
    for (int r = 0; r < 4; ++r) {
      float4 a4 = *(const float4*)&adjl[(w * 4 + r) * NPGL + c];
      acc[r] += a4.x * u0 + a4.y * u1v + a4.z * u2v + a4.w * u3v;
    }
  }
#pragma unroll
  for (int r = 0; r < 4; ++r) {
    const int lr = w * 4 + r;
    const int row = rowBase + lr;
    float ds = 0.f;
    for (int c = j; c < NPGL; c += 64) ds += adjl[lr * NPGL + c];
    ds = wredsum(ds);
    float disr = (ds > 0.f) ? (1.0f / sqrtf(ds)) : 0.f;
    float v = bchain(acc[r]);
    t[(size_t)row * 64 + j] = v;
    dt[(size_t)row * 64 + j] = disr * v;
    if (j == 0) dis[row] = disr;
  }
}

// ---- K4/K7: information score ----
template <int NPGL>
__global__ __launch_bounds__(256) void k_C(const float* __restrict__ adj,
                                           const float* __restrict__ t,
                                           const float* __restrict__ dt,
                                           const float* __restrict__ dis,
                                           float* __restrict__ score) {
  __shared__ float adjl[16 * NPGL];
  const int tid = threadIdx.x;
  const int w = tid >> 6, j = tid & 63;
  const int rowBase = blockIdx.x * 16;
  const int g = rowBase / NPGL;
  for (int f = tid; f < 16 * NPGL; f += 256) adjl[f] = adj[(size_t)rowBase * NPGL + f];
  __syncthreads();
  const float* dtg = dt + (size_t)g * NPGL * 64;
  float acc[4] = {0.f, 0.f, 0.f, 0.f};
  for (int c4 = 0; c4 < NPGL / 4; ++c4) {
    const int c = c4 * 4;
    float u0 = dtg[(size_t)(c + 0) * 64 + j];
    float u1v = dtg[(size_t)(c + 1) * 64 + j];
    float u2v = dtg[(size_t)(c + 2) * 64 + j];
    float u3v = dtg[(size_t)(c + 3) * 64 + j];
#pragma unroll
    for (int r = 0; r < 4; ++r) {
      float4 a4 = *(const float4*)&adjl[(w * 4 + r) * NPGL + c];
      acc[r] += a4.x * u0 + a4.y * u1v + a4.z * u2v + a4.w * u3v;
    }
  }
#pragma unroll
  for (int r = 0; r < 4; ++r) {
    const int row = rowBase + w * 4 + r;
    float d = fabsf(t[(size_t)row * 64 + j] - dis[row] * acc[r]);
    d = wredsum(d);
    if (j == 0) score[row] = d;
  }
}

// ---- K5: topk256 + xn + attention + adj2 + x1 readout + A2 (HypLinear 64) ----
__global__ __launch_bounds__(1024) void k_pool1(
    const float* __restrict__ score1, const float* __restrict__ t1,
    const float* __restrict__ adj1, const float* __restrict__ att1,
    const float* __restrict__ W2, const float* __restrict__ b2,
    float* __restrict__ adj2, float* __restrict__ x1, float* __restrict__ u2) {
  const int g = blockIdx.x, tid = threadIdx.x, w = tid >> 6, j = tid & 63;
  __shared__ float scS[256];
  __shared__ int selS[128];
  __shared__ float svalS[128], s1S[128], s2S[128];
  __shared__ float xnS[128 * 64];
  __shared__ float SM[64 * 65];
  if (tid < 256) scS[tid] = score1[(size_t)g * 256 + tid];
  for (int idx = tid; idx < 4096; idx += 1024) SM[(idx & 63) * 65 + (idx >> 6)] = W2[idx];
  __syncthreads();
  if (tid < 256) {
    float si = scS[tid];
    int rank = 0;
    for (int c = 0; c < 256; ++c) { float v = scS[c]; rank += (v > si) || (v == si && c < tid); }
    if (rank < 128) { selS[rank] = tid; svalS[rank] = si; }
  }
  __syncthreads();
  const float a1 = att1[j], a2 = att1[64 + j];
#pragma unroll
  for (int ii = 0; ii < 8; ++ii) {
    int i = w * 8 + ii;
    int li = selS[i];
    float tv = tanhf(svalS[i]);
    float v = t1[((size_t)g * 256 + li) * 64 + j] * tv;
    xnS[i * 64 + j] = v;
    float sa = wredsum(v * a1);
    float sb = wredsum(v * a2);
    if (j == 0) { s1S[i] = sa; s2S[i] = sb; }
  }
  __syncthreads();
  // structure learning -> adj2 (global; layer-2 B/C read it)
  for (int idx = tid; idx < 128 * 128; idx += 1024) {
    int ii = idx >> 7, jj = idx & 127;
    float e = s1S[ii] + s2S[jj];
    adj2[(size_t)g * 16384 + idx] =
        fmaxf(e, 0.f) + adj1[((size_t)g * 256 + selS[ii]) * 256 + selS[jj]];
  }
  // x1 readout (max | mean over 128 selected rows)
  if (tid < 64) {
    float mx = -1e30f, sm = 0.f;
    for (int r = 0; r < 128; ++r) { float v = xnS[r * 64 + tid]; mx = fmaxf(mx, v); sm += v; }
    x1[(size_t)g * 128 + tid] = mx;
    x1[(size_t)g * 128 + 64 + tid] = sm * (1.0f / 128.0f);
  }
  // A2: 16 waves x 8 rows, xn from LDS, W2^T from LDS via shuffle matvec
  float hbj, y2;
  biaschain(b2, j, hbj, y2);
  float xr[8], acc[8];
#pragma unroll
  for (int i = 0; i < 8; ++i) { xr[i] = xnS[(w * 8 + i) * 64 + j]; acc[i] = 0.f; }
#pragma unroll 8
  for (int t = 0; t < 64; ++t) {
    float wv = SM[t * 65 + j];
#pragma unroll
    for (int i = 0; i < 8; ++i) acc[i] += __shfl(xr[i], t) * wv;
  }
#pragma unroll
  for (int i = 0; i < 8; ++i)
    u2[((size_t)g * 128 + w * 8 + i) * 64 + j] = achain(xr[i], acc[i], hbj, y2);
}

// ---- K8: topk128 + xn2 + adj3(LDS) + x2 + A3 + B3 + x3 + MLP + log_softmax ----
__global__ __launch_bounds__(1024) void k_pool2(
    const float* __restrict__ score2, const float* __restrict__ t2,
    const float* __restrict__ adj2, const float* __restrict__ att2,
    const float* __restrict__ W3, const float* __restrict__ b3,
    const float* __restrict__ x1, const float* __restrict__ lw1,
    const float* __restrict__ lb1, const float* __restrict__ lw2,
    const float* __restrict__ lb2, const float* __restrict__ lw3,
    const float* __restrict__ lb3, float* __restrict__ out) {
  const int g = blockIdx.x, tid = threadIdx.x, w = tid >> 6, j = tid & 63;
  __shared__ float scS[128];
  __shared__ int selS[64];
  __shared__ float svalS[64], s1S[64], s2S[64];
  __shared__ float xnS[64 * 64], adj3S[64 * 64], uS[64 * 64], SM[64 * 65];
  __shared__ float rS[128], h1S[64], h2S[32], zS[8], x2S[128], x3S[128];
  if (tid < 128) scS[tid] = score2[(size_t)g * 128 + tid];
  for (int idx = tid; idx < 4096; idx += 1024) SM[(idx & 63) * 65 + (idx >> 6)] = W3[idx];
  __syncthreads();
  if (tid < 128) {
    float si = scS[tid];
    int rank = 0;
    for (int c = 0; c < 128; ++c) { float v = scS[c]; rank += (v > si) || (v == si && c < tid); }
    if (rank < 64) { selS[rank] = tid; svalS[rank] = si; }
  }
  __syncthreads();
  const float a1 = att2[j], a2 = att2[64 + j];
#pragma unroll
  for (int ii = 0; ii < 4; ++ii) {
    int i = w * 4 + ii;
    int li = selS[i];
    float tv = tanhf(svalS[i]);
    float v = t2[((size_t)g * 128 + li) * 64 + j] * tv;
    xnS[i * 64 + j] = v;
    float sa = wredsum(v * a1);
    float sb = wredsum(v * a2);
    if (j == 0) { s1S[i] = sa; s2S[i] = sb; }
  }
  __syncthreads();
  // adj3 in LDS
  for (int idx = tid; idx < 4096; idx += 1024) {
    int ii = idx >> 6, jj = idx & 63;
    adj3S[idx] = fmaxf(s1S[ii] + s2S[jj], 0.f) +
                 adj2[((size_t)g * 128 + selS[ii]) * 128 + selS[jj]];
  }
  // x2 readout
  if (tid < 64) {
    float mx = -1e30f, sm = 0.f;
    for (int r = 0; r < 64; ++r) { float v = xnS[r * 64 + tid]; mx = fmaxf(mx, v); sm += v; }
    x2S[tid] = mx;
    x2S[64 + tid] = sm * (1.0f / 64.0f);
  }
  // A3: 16 waves x 4 rows
  float hbj, y2;
  biaschain(b3, j, hbj, y2);
  float xr[4], acc[4];
#pragma unroll
  for (int i = 0; i < 4; ++i) { xr[i] = xnS[(w * 4 + i) * 64 + j]; acc[i] = 0.f; }
#pragma unroll 8
  for (int t = 0; t < 64; ++t) {
    float wv = SM[t * 65 + j];
#pragma unroll
    for (int i = 0; i < 4; ++i) acc[i] += __shfl(xr[i], t) * wv;
  }
#pragma unroll
  for (int i = 0; i < 4; ++i) uS[(w * 4 + i) * 64 + j] = achain(xr[i], acc[i], hbj, y2);
  __syncthreads();  // uS + adj3S complete; xnS free to overwrite
  // B3: dense 64x64 agg entirely in LDS, then hyperbolic chain
#pragma unroll
  for (int ii = 0; ii < 4; ++ii) {
    int r = w * 4 + ii;
    float accv = 0.f;
#pragma unroll 8
    for (int c = 0; c < 64; ++c) accv += adj3S[r * 64 + c] * uS[c * 64 + j];
    float v = bchain(accv);
    xnS[r * 64 + j] = v;  // reuse as t3 storage
  }
  __syncthreads();
  // x3 readout
  if (tid < 64) {
    float mx = -1e30f, sm = 0.f;
    for (int r = 0; r < 64; ++r) { float v = xnS[r * 64 + tid]; mx = fmaxf(mx, v); sm += v; }
    x3S[tid] = mx;
    x3S[64 + tid] = sm * (1.0f / 64.0f);
  }
  __syncthreads();
  // MLP head
  if (tid < 128)
    rS[tid] = fmaxf(x1[(size_t)g * 128 + tid], 0.f) + fmaxf(x2S[tid], 0.f) + fmaxf(x3S[tid], 0.f);
  __syncthreads();
  if (tid < 64) {
    float a = lb1[tid];
    for (int t = 0; t < 128; ++t) a += rS[t] * lw1[(size_t)tid * 128 + t];
    h1S[tid] = fmaxf(a, 0.f);
  }
  __syncthreads();
  if (tid < 32) {
    float a = lb2[tid];
    for (int t = 0; t < 64; ++t) a += h1S[t] * lw2[(size_t)tid * 64 + t];
    h2S[tid] = fmaxf(a, 0.f);
  }
  __syncthreads();
  if (tid < 6) {
    float a = lb3[tid];
    for (int t = 0; t < 32; ++t) a += h2S[t] * lw3[(size_t)tid * 32 + t];
    zS[tid] = a;
  }
  __syncthreads();
  if (tid < 6) {
    float m = zS[0];
    for (int c = 1; c < 6; ++c) m = fmaxf(m, zS[c]);
    float se = 0.f;
    for (int c = 0; c < 6; ++c) se += expf(zS[c] - m);
    out[(size_t)g * 6 + tid] = zS[tid] - m - logf(se);
  }
}

extern "C" void kernel_launch(void* const* d_in, const int* in_sizes, int n_in,
                              void* d_out, int out_size, void* d_ws, size_t ws_size,
                              hipStream_t stream) {
  const float* x = (const float*)d_in[0];
  const int* ei = (const int*)d_in[1];
  const float* W1 = (const float*)d_in[2];
  const float* b1 = (const float*)d_in[3];
  const float* W2 = (const float*)d_in[4];
  const float* b2 = (const float*)d_in[5];
  const float* W3 = (const float*)d_in[6];
  const float* b3 = (const float*)d_in[7];
  const float* att1 = (const float*)d_in[8];
  const float* att2 = (const float*)d_in[9];
  const float* lw1 = (const float*)d_in[10];
  const float* lb1 = (const float*)d_in[11];
  const float* lw2 = (const float*)d_in[12];
  const float* lb2 = (const float*)d_in[13];
  const float* lw3 = (const float*)d_in[14];
  const float* lb3 = (const float*)d_in[15];
  float* out = (float*)d_out;
  const int nE = in_sizes[1] / 2;

  float* p = (float*)d_ws;
  float* srow = p;   p += 8192;
  float* adj1 = p;   p += (size_t)32 * 256 * 256;
  float* adj2 = p;   p += (size_t)32 * 128 * 128;
  float* u1 = p;     p += (size_t)8192 * 64;
  float* t1 = p;     p += (size_t)8192 * 64;
  float* dt1 = p;    p += (size_t)8192 * 64;
  float* dis1 = p;   p += 8192;
  float* score1 = p; p += 8192;
  float* u2 = p;     p += (size_t)4096 * 64;
  float* t2 = p;     p += (size_t)4096 * 64;
  float* dt2 = p;    p += (size_t)4096 * 64;
  float* dis2 = p;   p += 4096;
  float* score2 = p; p += 4096;
  float* x1 = p;     p += 32 * 128;

  k_A1<<<1024, 256, 0, stream>>>(x, W1, b1, adj1, u1, srow);
  k_edges<<<128, 256, 0, stream>>>(ei, ei + nE, srow, adj1, nE);
  k_B<256><<<512, 256, 0, stream>>>(adj1, u1, t1, dt1, dis1);
  k_C<256><<<512, 256, 0, stream>>>(adj1, t1, dt1, dis1, score1);
  k_pool1<<<32, 1024, 0, stream>>>(score1, t1, adj1, att1, W2, b2, adj2, x1, u2);
  k_B<128><<<256, 256, 0, stream>>>(adj2, u2, t2, dt2, dis2);
  k_C<128><<<256, 256, 0, stream>>>(adj2, t2, dt2, dis2, score2);
  k_pool2<<<32, 1024, 0, stream>>>(score2, t2, adj2, att2, W3, b3, x1,
                                   lw1, lb1, lw2, lb2, lw3, lb3, out);
}

// Round 5
// 301.462 us; speedup vs baseline: 2.5331x; 1.1164x over previous
//
#include <hip/hip_runtime.h>
#include <math.h>

#define MAXN 0.996f /* (1-PROJ_EPS)/sqrt(c) */

__device__ __forceinline__ float wredsum(float v) {
#pragma unroll
  for (int o = 32; o > 0; o >>= 1) v += __shfl_xor(v, o);
  return v;
}

__device__ __forceinline__ float artanh_f(float x) {
  x = fminf(fmaxf(x, -1.0f + 1e-7f), 1.0f - 1e-7f);
  return 0.5f * (log1pf(x) - log1pf(-x));
}

// B-chain: expmap0 -> proj -> logmap0 -> relu -> expmap0 -> proj -> logmap0
__device__ __forceinline__ float bchain(float acc) {
  float n0 = sqrtf(wredsum(acc * acc));
  float u0 = fmaxf(n0, 1e-15f);
  float e1 = tanhf(u0) / u0;
  float c1 = fmaxf(e1 * n0, 1e-15f);
  float v = acc * e1;
  if (c1 > MAXN) { v *= MAXN / c1; c1 = MAXN; }
  v *= artanh_f(c1) / c1;
  v = fmaxf(v, 0.f);
  float n2 = sqrtf(wredsum(v * v));
  float u2 = fmaxf(n2, 1e-15f);
  float e2 = tanhf(u2) / u2;
  float c2 = fmaxf(e2 * n2, 1e-15f);
  v *= e2;
  if (c2 > MAXN) { v *= MAXN / c2; c2 = MAXN; }
  v *= artanh_f(c2) / c2;
  return v;
}

// A-chain epilogue: mobius_matvec tail + proj + mobius_add(bias) + proj + logmap0
__device__ __forceinline__ float achain(float xrv, float accv, float hbj, float y2) {
  float nx = sqrtf(wredsum(xrv * xrv));
  float un = fmaxf(nx, 1e-15f);
  float s1 = tanhf(un) / un;
  float nn = fmaxf(s1 * nx, 1e-15f);
  float s2 = (nn > MAXN) ? MAXN / nn : 1.0f;
  float alpha = s1 * s2;
  float xnm = fmaxf(fminf(nn, MAXN), 1e-15f);
  float mxj = alpha * accv;
  float mxn = fmaxf(sqrtf(wredsum(mxj * mxj)), 1e-15f);
  float hj = (tanhf(mxn / xnm * artanh_f(xnm)) / mxn) * mxj;
  float hn = fmaxf(sqrtf(wredsum(hj * hj)), 1e-15f);
  if (hn > MAXN) hj *= MAXN / hn;
  float x2v = wredsum(hj * hj);
  float xyv = wredsum(hj * hbj);
  float num = (1.f + 2.f * xyv + y2) * hj + (1.f - x2v) * hbj;
  float den = fmaxf(1.f + 2.f * xyv + x2v * y2, 1e-15f);
  float aj = num / den;
  float an = fmaxf(sqrtf(wredsum(aj * aj)), 1e-15f);
  float pn = an;
  if (an > MAXN) { aj *= MAXN / an; pn = MAXN; }
  return (artanh_f(pn) / pn) * aj;
}

__device__ __forceinline__ void biaschain(const float* bp, int j, float& hbj, float& y2) {
  float bj = bp[j];
  float nb = sqrtf(wredsum(bj * bj));
  float ub = fmaxf(nb, 1e-15f), eb = tanhf(ub) / ub, cb = fmaxf(eb * nb, 1e-15f);
  hbj = bj * eb * ((cb > MAXN) ? MAXN / cb : 1.0f);
  y2 = wredsum(hbj * hbj);
}

// ---- K1: zero adj1 slice + layer-1 HypLinear (IND=128) + per-row sums ----
__global__ __launch_bounds__(256) void k_A1(const float* __restrict__ x,
                                            const float* __restrict__ W1,
                                            const float* __restrict__ b1,
                                            float* __restrict__ adj1,
                                            float* __restrict__ u1,
                                            float* __restrict__ srow) {
  constexpr int IND = 128, WSTR = 132;
  __shared__ float Wl[64 * WSTR];
  __shared__ float xsh[8 * IND];
  const int tid = threadIdx.x, w = tid >> 6, j = tid & 63;
  const int rowBase = blockIdx.x * 8;
  {
    float4 z = {0.f, 0.f, 0.f, 0.f};
    float4* a4 = (float4*)adj1 + (size_t)blockIdx.x * 512;
    a4[tid] = z;
    a4[tid + 256] = z;
  }
  for (int f = tid; f < 64 * IND; f += 256) { int jj = f >> 7, t = f & 127; Wl[jj * WSTR + t] = W1[f]; }
  for (int f = tid; f < 8 * IND; f += 256) xsh[f] = x[(size_t)rowBase * IND + f];
  __syncthreads();
  float hbj, y2;
  biaschain(b1, j, hbj, y2);
  const float4* wrow = (const float4*)(Wl + j * WSTR);
#pragma unroll
  for (int rr = 0; rr < 2; ++rr) {
    const int lr = w * 2 + rr;
    const float* xs = xsh + lr * IND;
    float v0 = xs[j], v1 = xs[64 + j];
    float sr = wredsum(v0 + v1);
    float nx = sqrtf(wredsum(v0 * v0 + v1 * v1));
    float un = fmaxf(nx, 1e-15f);
    float s1 = tanhf(un) / un;
    float nn = fmaxf(s1 * nx, 1e-15f);
    float s2 = (nn > MAXN) ? MAXN / nn : 1.0f;
    float alpha = s1 * s2;
    float xnm = fmaxf(fminf(nn, MAXN), 1e-15f);
    const float4* xv4 = (const float4*)xs;
    float y = 0.f;
#pragma unroll
    for (int t4 = 0; t4 < IND / 4; ++t4) {
      float4 w4 = wrow[t4];
      float4 v4 = xv4[t4];
      y += w4.x * v4.x + w4.y * v4.y + w4.z * v4.z + w4.w * v4.w;
    }
    float mxj = alpha * y;
    float mxn = fmaxf(sqrtf(wredsum(mxj * mxj)), 1e-15f);
    float hj = (tanhf(mxn / xnm * artanh_f(xnm)) / mxn) * mxj;
    float hn = fmaxf(sqrtf(wredsum(hj * hj)), 1e-15f);
    if (hn > MAXN) hj *= MAXN / hn;
    float x2v = wredsum(hj * hj);
    float xyv = wredsum(hj * hbj);
    float num = (1.f + 2.f * xyv + y2) * hj + (1.f - x2v) * hbj;
    float den = fmaxf(1.f + 2.f * xyv + x2v * y2, 1e-15f);
    float aj = num / den;
    float an = fmaxf(sqrtf(wredsum(aj * aj)), 1e-15f);
    float pn = an;
    if (an > MAXN) { aj *= MAXN / an; pn = MAXN; }
    const int row = rowBase + lr;
    if (j == 0) srow[row] = sr;
    u1[(size_t)row * 64 + j] = (artanh_f(pn) / pn) * aj;
  }
}

// ---- K2: scatter edges into block-diagonal adj1 ----
__global__ void k_edges(const int* __restrict__ er, const int* __restrict__ ec,
                        const float* __restrict__ srow, float* __restrict__ adj1, int nE) {
  for (int e = blockIdx.x * blockDim.x + threadIdx.x; e < nE; e += gridDim.x * blockDim.x) {
    int r = er[e], c = ec[e];
    adj1[(size_t)r * 256 + (c & 255)] = 0.5f * (srow[r] + srow[c]);
  }
}

// ---- HypAgg+HypAct chain; emits t, dt=dis*t, dis ----
template <int NPGL>
__global__ __launch_bounds__(256) void k_B(const float* __restrict__ adj,
                                           const float* __restrict__ u, float* __restrict__ t,
                                           float* __restrict__ dt, float* __restrict__ dis) {
  __shared__ float adjl[16 * NPGL];
  const int tid = threadIdx.x;
  const int w = tid >> 6, j = tid & 63;
  const int rowBase = blockIdx.x * 16;
  const int g = rowBase / NPGL;
  for (int f = tid; f < 16 * NPGL; f += 256) adjl[f] = adj[(size_t)rowBase * NPGL + f];
  __syncthreads();
  const float* ug = u + (size_t)g * NPGL * 64;
  float acc[4] = {0.f, 0.f, 0.f, 0.f};
  for (int c4 = 0; c4 < NPGL / 4; ++c4) {
    const int c = c4 * 4;
    float u0 = ug[(size_t)(c + 0) * 64 + j];
    float u1v = ug[(size_t)(c + 1) * 64 + j];
    float u2v = ug[(size_t)(c + 2) * 64 + j];
    float u3v = ug[(size_t)(c + 3) * 64 + j];
#pragma unroll
    for (int r = 0; r < 4; ++r) {
      float4 a4 = *(const float4*)&adjl[(w * 4 + r) * NPGL + c];
      acc[r] += a4.x * u0 + a4.y * u1v + a4.z * u2v + a4.w * u3v;
    }
  }
#pragma unroll
  for (int r = 0; r < 4; ++r) {
    const int lr = w * 4 + r;
    const int row = rowBase + lr;
    float ds = 0.f;
    for (int c = j; c < NPGL; c += 64) ds += adjl[lr * NPGL + c];
    ds = wredsum(ds);
    float disr = (ds > 0.f) ? (1.0f / sqrtf(ds)) : 0.f;
    float v = bchain(acc[r]);
    t[(size_t)row * 64 + j] = v;
    dt[(size_t)row * 64 + j] = disr * v;
    if (j == 0) dis[row] = disr;
  }
}

// ---- information score ----
template <int NPGL>
__global__ __launch_bounds__(256) void k_C(const float* __restrict__ adj,
                                           const float* __restrict__ t,
                                           const float* __restrict__ dt,
                                           const float* __restrict__ dis,
                                           float* __restrict__ score) {
  __shared__ float adjl[16 * NPGL];
  const int tid = threadIdx.x;
  const int w = tid >> 6, j = tid & 63;
  const int rowBase = blockIdx.x * 16;
  const int g = rowBase / NPGL;
  for (int f = tid; f < 16 * NPGL; f += 256) adjl[f] = adj[(size_t)rowBase * NPGL + f];
  __syncthreads();
  const float* dtg = dt + (size_t)g * NPGL * 64;
  float acc[4] = {0.f, 0.f, 0.f, 0.f};
  for (int c4 = 0; c4 < NPGL / 4; ++c4) {
    const int c = c4 * 4;
    float u0 = dtg[(size_t)(c + 0) * 64 + j];
    float u1v = dtg[(size_t)(c + 1) * 64 + j];
    float u2v = dtg[(size_t)(c + 2) * 64 + j];
    float u3v = dtg[(size_t)(c + 3) * 64 + j];
#pragma unroll
    for (int r = 0; r < 4; ++r) {
      float4 a4 = *(const float4*)&adjl[(w * 4 + r) * NPGL + c];
      acc[r] += a4.x * u0 + a4.y * u1v + a4.z * u2v + a4.w * u3v;
    }
  }
#pragma unroll
  for (int r = 0; r < 4; ++r) {
    const int row = rowBase + w * 4 + r;
    float d = fabsf(t[(size_t)row * 64 + j] - dis[row] * acc[r]);
    d = wredsum(d);
    if (j == 0) score[row] = d;
  }
}

// ---- per-graph top-k + xn gather + attention scalars + readout (32 blocks, light) ----
template <int NPGL>
__global__ __launch_bounds__(256) void k_top(
    const float* __restrict__ score, const float* __restrict__ t,
    const float* __restrict__ att, int* __restrict__ selG,
    float* __restrict__ s1G, float* __restrict__ s2G,
    float* __restrict__ xnG, float* __restrict__ xr) {
  constexpr int K = NPGL / 2;
  const int g = blockIdx.x, tid = threadIdx.x, w = tid >> 6, j = tid & 63;
  __shared__ float scS[NPGL];
  __shared__ int selS[K];
  __shared__ float svalS[K];
  __shared__ float xnS[K * 64];
  for (int i = tid; i < NPGL; i += 256) scS[i] = score[(size_t)g * NPGL + i];
  __syncthreads();
  if (tid < NPGL) {
    float si = scS[tid];
    int rank = 0;
    for (int c = 0; c < NPGL; ++c) { float v = scS[c]; rank += (v > si) || (v == si && c < tid); }
    if (rank < K) { selS[rank] = tid; svalS[rank] = si; }
  }
  __syncthreads();
  const float a1 = att[j], a2 = att[64 + j];
  for (int i = w * (K / 4); i < (w + 1) * (K / 4); ++i) {
    int li = selS[i];
    float tv = tanhf(svalS[i]);
    float v = t[((size_t)g * NPGL + li) * 64 + j] * tv;
    xnS[i * 64 + j] = v;
    xnG[((size_t)g * K + i) * 64 + j] = v;
    float sa = wredsum(v * a1);
    float sb = wredsum(v * a2);
    if (j == 0) {
      s1G[(size_t)g * K + i] = sa;
      s2G[(size_t)g * K + i] = sb;
      selG[(size_t)g * K + i] = li;
    }
  }
  __syncthreads();
  if (tid < 64) {
    float mx = -1e30f, sm = 0.f;
    for (int r = 0; r < K; ++r) { float v = xnS[r * 64 + tid]; mx = fmaxf(mx, v); sm += v; }
    xr[(size_t)g * 128 + tid] = mx;
    xr[(size_t)g * 128 + 64 + tid] = sm * (1.0f / K);
  }
}

// ---- wide: structure-learning adj build + HypLinear achain (2 rows/wave) ----
template <int NPGL, int ADJB>
__global__ __launch_bounds__(256) void k_mid(
    const int* __restrict__ selG, const float* __restrict__ s1G,
    const float* __restrict__ s2G, const float* __restrict__ adjO,
    const float* __restrict__ xnG, const float* __restrict__ W,
    const float* __restrict__ b, float* __restrict__ adjN, float* __restrict__ uN) {
  constexpr int K = NPGL / 2;
  const int tid = threadIdx.x, w = tid >> 6, j = tid & 63;
  if (blockIdx.x < ADJB) {
    const int total = 32 * K * K;
    for (int idx = blockIdx.x * 256 + tid; idx < total; idx += ADJB * 256) {
      int g = idx / (K * K);
      int r = idx - g * K * K;
      int ii = r / K, jj = r - ii * K;
      float e = s1G[(size_t)g * K + ii] + s2G[(size_t)g * K + jj];
      adjN[idx] = fmaxf(e, 0.f) +
                  adjO[((size_t)g * NPGL + selG[(size_t)g * K + ii]) * NPGL +
                       selG[(size_t)g * K + jj]];
    }
    return;
  }
  __shared__ float SM[64 * 65];
  for (int idx = tid; idx < 4096; idx += 256) SM[(idx & 63) * 65 + (idx >> 6)] = W[idx];
  __syncthreads();
  float hbj, y2;
  biaschain(b, j, hbj, y2);
  const int rowBase = (blockIdx.x - ADJB) * 8;
#pragma unroll
  for (int rr = 0; rr < 2; ++rr) {
    const int r = rowBase + w * 2 + rr;  // global pooled row in [0, 32*K)
    float xrv = xnG[(size_t)r * 64 + j];
    float acc = 0.f;
#pragma unroll 8
    for (int t = 0; t < 64; ++t) acc += __shfl(xrv, t) * SM[t * 65 + j];
    uN[(size_t)r * 64 + j] = achain(xrv, acc, hbj, y2);
  }
}

// ---- final: B3 agg (all-LDS) + x3 readout + MLP + log_softmax ----
__global__ __launch_bounds__(1024) void k_fin(
    const float* __restrict__ adj3, const float* __restrict__ u3,
    const float* __restrict__ x1G, const float* __restrict__ x2G,
    const float* __restrict__ lw1, const float* __restrict__ lb1,
    const float* __restrict__ lw2, const float* __restrict__ lb2,
    const float* __restrict__ lw3, const float* __restrict__ lb3,
    float* __restrict__ out) {
  const int g = blockIdx.x, tid = threadIdx.x, w = tid >> 6, j = tid & 63;
  __shared__ float uS[64 * 64];
  __shared__ float t3S[64 * 64];
  __shared__ float rS[128], h1S[64], h2S[32], zS[8], x3S[128];
  for (int idx = tid; idx < 4096; idx += 1024) uS[idx] = u3[(size_t)g * 4096 + idx];
  __syncthreads();
#pragma unroll
  for (int ii = 0; ii < 4; ++ii) {
    int r = w * 4 + ii;
    float arow = adj3[(size_t)g * 4096 + r * 64 + j];
    float acc = 0.f;
#pragma unroll 8
    for (int c = 0; c < 64; ++c) acc += __shfl(arow, c) * uS[c * 64 + j];
    t3S[r * 64 + j] = bchain(acc);
  }
  __syncthreads();
  if (tid < 64) {
    float mx = -1e30f, sm = 0.f;
    for (int r = 0; r < 64; ++r) { float v = t3S[r * 64 + tid]; mx = fmaxf(mx, v); sm += v; }
    x3S[tid] = mx;
    x3S[64 + tid] = sm * (1.0f / 64.0f);
  }
  __syncthreads();
  if (tid < 128)
    rS[tid] = fmaxf(x1G[(size_t)g * 128 + tid], 0.f) + fmaxf(x2G[(size_t)g * 128 + tid], 0.f) +
              fmaxf(x3S[tid], 0.f);
  __syncthreads();
  if (tid < 64) {
    float a = lb1[tid];
    for (int t = 0; t < 128; ++t) a += rS[t] * lw1[(size_t)tid * 128 + t];
    h1S[tid] = fmaxf(a, 0.f);
  }
  __syncthreads();
  if (tid < 32) {
    float a = lb2[tid];
    for (int t = 0; t < 64; ++t) a += h1S[t] * lw2[(size_t)tid * 64 + t];
    h2S[tid] = fmaxf(a, 0.f);
  }
  __syncthreads();
  if (tid < 6) {
    float a = lb3[tid];
    for (int t = 0; t < 32; ++t) a += h2S[t] * lw3[(size_t)tid * 32 + t];
    zS[tid] = a;
  }
  __syncthreads();
  if (tid < 6) {
    float m = zS[0];
    for (int c = 1; c < 6; ++c) m = fmaxf(m, zS[c]);
    float se = 0.f;
    for (int c = 0; c < 6; ++c) se += expf(zS[c] - m);
    out[(size_t)g * 6 + tid] = zS[tid] - m - logf(se);
  }
}

extern "C" void kernel_launch(void* const* d_in, const int* in_sizes, int n_in,
                              void* d_out, int out_size, void* d_ws, size_t ws_size,
                              hipStream_t stream) {
  const float* x = (const float*)d_in[0];
  const int* ei = (const int*)d_in[1];
  const float* W1 = (const float*)d_in[2];
  const float* b1 = (const float*)d_in[3];
  const float* W2 = (const float*)d_in[4];
  const float* b2 = (const float*)d_in[5];
  const float* W3 = (const float*)d_in[6];
  const float* b3 = (const float*)d_in[7];
  const float* att1 = (const float*)d_in[8];
  const float* att2 = (const float*)d_in[9];
  const float* lw1 = (const float*)d_in[10];
  const float* lb1 = (const float*)d_in[11];
  const float* lw2 = (const float*)d_in[12];
  const float* lb2 = (const float*)d_in[13];
  const float* lw3 = (const float*)d_in[14];
  const float* lb3 = (const float*)d_in[15];
  float* out = (float*)d_out;
  const int nE = in_sizes[1] / 2;

  float* p = (float*)d_ws;
  float* srow = p;   p += 8192;
  float* adj1 = p;   p += (size_t)32 * 256 * 256;
  float* adj2 = p;   p += (size_t)32 * 128 * 128;
  float* adj3 = p;   p += (size_t)32 * 64 * 64;
  float* u1 = p;     p += (size_t)8192 * 64;
  float* t1 = p;     p += (size_t)8192 * 64;
  float* dt1 = p;    p += (size_t)8192 * 64;
  float* dis1 = p;   p += 8192;
  float* score1 = p; p += 8192;
  float* xn1 = p;    p += (size_t)4096 * 64;
  float* u2 = p;     p += (size_t)4096 * 64;
  float* t2 = p;     p += (size_t)4096 * 64;
  float* dt2 = p;    p += (size_t)4096 * 64;
  float* dis2 = p;   p += 4096;
  float* score2 = p; p += 4096;
  float* xn2 = p;    p += (size_t)2048 * 64;
  float* u3 = p;     p += (size_t)2048 * 64;
  float* s1a = p;    p += 4096;
  float* s2a = p;    p += 4096;
  float* s1b = p;    p += 2048;
  float* s2b = p;    p += 2048;
  float* x1G = p;    p += 32 * 128;
  float* x2G = p;    p += 32 * 128;
  int* sel1 = (int*)p; p += 4096;
  int* sel2 = (int*)p; p += 2048;

  k_A1<<<1024, 256, 0, stream>>>(x, W1, b1, adj1, u1, srow);
  k_edges<<<128, 256, 0, stream>>>(ei, ei + nE, srow, adj1, nE);
  k_B<256><<<512, 256, 0, stream>>>(adj1, u1, t1, dt1, dis1);
  k_C<256><<<512, 256, 0, stream>>>(adj1, t1, dt1, dis1, score1);
  k_top<256><<<32, 256, 0, stream>>>(score1, t1, att1, sel1, s1a, s2a, xn1, x1G);
  // adj2 build (256 blocks) + A2 achain (4096 rows / 8 per block = 512 blocks)
  k_mid<256, 256><<<768, 256, 0, stream>>>(sel1, s1a, s2a, adj1, xn1, W2, b2, adj2, u2);
  k_B<128><<<256, 256, 0, stream>>>(adj2, u2, t2, dt2, dis2);
  k_C<128><<<256, 256, 0, stream>>>(adj2, t2, dt2, dis2, score2);
  k_top<128><<<32, 256, 0, stream>>>(score2, t2, att2, sel2, s1b, s2b, xn2, x2G);
  // adj3 build (64 blocks) + A3 achain (2048 rows / 8 per block = 256 blocks)
  k_mid<128, 64><<<320, 256, 0, stream>>>(sel2, s1b, s2b, adj2, xn2, W3, b3, adj3, u3);
  k_fin<<<32, 1024, 0, stream>>>(adj3, u3, x1G, x2G, lw1, lb1, lw2, lb2, lw3, lb3, out);
}

// Round 6
// 267.661 us; speedup vs baseline: 2.8530x; 1.1263x over previous
//
#include <hip/hip_runtime.h>
#include <math.h>

#define MAXN 0.996f /* (1-PROJ_EPS)/sqrt(c) */

__device__ __forceinline__ float wredsum(float v) {
#pragma unroll
  for (int o = 32; o > 0; o >>= 1) v += __shfl_xor(v, o);
  return v;
}

__device__ __forceinline__ float artanh_f(float x) {
  x = fminf(fmaxf(x, -1.0f + 1e-7f), 1.0f - 1e-7f);
  return 0.5f * (log1pf(x) - log1pf(-x));
}

// B-chain: expmap0 -> proj -> logmap0 -> relu -> expmap0 -> proj -> logmap0
__device__ __forceinline__ float bchain(float acc) {
  float n0 = sqrtf(wredsum(acc * acc));
  float u0 = fmaxf(n0, 1e-15f);
  float e1 = tanhf(u0) / u0;
  float c1 = fmaxf(e1 * n0, 1e-15f);
  float v = acc * e1;
  if (c1 > MAXN) { v *= MAXN / c1; c1 = MAXN; }
  v *= artanh_f(c1) / c1;
  v = fmaxf(v, 0.f);
  float n2 = sqrtf(wredsum(v * v));
  float u2 = fmaxf(n2, 1e-15f);
  float e2 = tanhf(u2) / u2;
  float c2 = fmaxf(e2 * n2, 1e-15f);
  v *= e2;
  if (c2 > MAXN) { v *= MAXN / c2; c2 = MAXN; }
  v *= artanh_f(c2) / c2;
  return v;
}

// A-chain epilogue: mobius_matvec tail + proj + mobius_add(bias) + proj + logmap0
__device__ __forceinline__ float achain(float xrv, float accv, float hbj, float y2) {
  float nx = sqrtf(wredsum(xrv * xrv));
  float un = fmaxf(nx, 1e-15f);
  float s1 = tanhf(un) / un;
  float nn = fmaxf(s1 * nx, 1e-15f);
  float s2 = (nn > MAXN) ? MAXN / nn : 1.0f;
  float alpha = s1 * s2;
  float xnm = fmaxf(fminf(nn, MAXN), 1e-15f);
  float mxj = alpha * accv;
  float mxn = fmaxf(sqrtf(wredsum(mxj * mxj)), 1e-15f);
  float hj = (tanhf(mxn / xnm * artanh_f(xnm)) / mxn) * mxj;
  float hn = fmaxf(sqrtf(wredsum(hj * hj)), 1e-15f);
  if (hn > MAXN) hj *= MAXN / hn;
  float x2v = wredsum(hj * hj);
  float xyv = wredsum(hj * hbj);
  float num = (1.f + 2.f * xyv + y2) * hj + (1.f - x2v) * hbj;
  float den = fmaxf(1.f + 2.f * xyv + x2v * y2, 1e-15f);
  float aj = num / den;
  float an = fmaxf(sqrtf(wredsum(aj * aj)), 1e-15f);
  float pn = an;
  if (an > MAXN) { aj *= MAXN / an; pn = MAXN; }
  return (artanh_f(pn) / pn) * aj;
}

__device__ __forceinline__ void biaschain(const float* bp, int j, float& hbj, float& y2) {
  float bj = bp[j];
  float nb = sqrtf(wredsum(bj * bj));
  float ub = fmaxf(nb, 1e-15f), eb = tanhf(ub) / ub, cb = fmaxf(eb * nb, 1e-15f);
  hbj = bj * eb * ((cb > MAXN) ? MAXN / cb : 1.0f);
  y2 = wredsum(hbj * hbj);
}

// ---- K1: zero adj1 slice + layer-1 HypLinear (IND=128) + per-row sums ----
__global__ __launch_bounds__(256) void k_A1(const float* __restrict__ x,
                                            const float* __restrict__ W1,
                                            const float* __restrict__ b1,
                                            float* __restrict__ adj1,
                                            float* __restrict__ u1,
                                            float* __restrict__ srow) {
  constexpr int IND = 128, WSTR = 132;
  __shared__ float Wl[64 * WSTR];
  __shared__ float xsh[8 * IND];
  const int tid = threadIdx.x, w = tid >> 6, j = tid & 63;
  const int rowBase = blockIdx.x * 8;
  {
    float4 z = {0.f, 0.f, 0.f, 0.f};
    float4* a4 = (float4*)adj1 + (size_t)blockIdx.x * 512;
    a4[tid] = z;
    a4[tid + 256] = z;
  }
  for (int f = tid; f < 64 * IND; f += 256) { int jj = f >> 7, t = f & 127; Wl[jj * WSTR + t] = W1[f]; }
  for (int f = tid; f < 8 * IND; f += 256) xsh[f] = x[(size_t)rowBase * IND + f];
  __syncthreads();
  float hbj, y2;
  biaschain(b1, j, hbj, y2);
  const float4* wrow = (const float4*)(Wl + j * WSTR);
#pragma unroll
  for (int rr = 0; rr < 2; ++rr) {
    const int lr = w * 2 + rr;
    const float* xs = xsh + lr * IND;
    float v0 = xs[j], v1 = xs[64 + j];
    float sr = wredsum(v0 + v1);
    float nx = sqrtf(wredsum(v0 * v0 + v1 * v1));
    float un = fmaxf(nx, 1e-15f);
    float s1 = tanhf(un) / un;
    float nn = fmaxf(s1 * nx, 1e-15f);
    float s2 = (nn > MAXN) ? MAXN / nn : 1.0f;
    float alpha = s1 * s2;
    float xnm = fmaxf(fminf(nn, MAXN), 1e-15f);
    const float4* xv4 = (const float4*)xs;
    float y = 0.f;
#pragma unroll
    for (int t4 = 0; t4 < IND / 4; ++t4) {
      float4 w4 = wrow[t4];
      float4 v4 = xv4[t4];
      y += w4.x * v4.x + w4.y * v4.y + w4.z * v4.z + w4.w * v4.w;
    }
    float mxj = alpha * y;
    float mxn = fmaxf(sqrtf(wredsum(mxj * mxj)), 1e-15f);
    float hj = (tanhf(mxn / xnm * artanh_f(xnm)) / mxn) * mxj;
    float hn = fmaxf(sqrtf(wredsum(hj * hj)), 1e-15f);
    if (hn > MAXN) hj *= MAXN / hn;
    float x2v = wredsum(hj * hj);
    float xyv = wredsum(hj * hbj);
    float num = (1.f + 2.f * xyv + y2) * hj + (1.f - x2v) * hbj;
    float den = fmaxf(1.f + 2.f * xyv + x2v * y2, 1e-15f);
    float aj = num / den;
    float an = fmaxf(sqrtf(wredsum(aj * aj)), 1e-15f);
    float pn = an;
    if (an > MAXN) { aj *= MAXN / an; pn = MAXN; }
    const int row = rowBase + lr;
    if (j == 0) srow[row] = sr;
    u1[(size_t)row * 64 + j] = (artanh_f(pn) / pn) * aj;
  }
}

// ---- K2: scatter edges into block-diagonal adj1 ----
__global__ void k_edges(const int* __restrict__ er, const int* __restrict__ ec,
                        const float* __restrict__ srow, float* __restrict__ adj1, int nE) {
  for (int e = blockIdx.x * blockDim.x + threadIdx.x; e < nE; e += gridDim.x * blockDim.x) {
    int r = er[e], c = ec[e];
    adj1[(size_t)r * 256 + (c & 255)] = 0.5f * (srow[r] + srow[c]);
  }
}

// ---- K3: sparse HypAgg+HypAct; builds CSR (ballot-compact) and stores it for k_Cs ----
// One wave per row; 4 rows per block. Ascending-c accumulation skipping exact zeros is
// bit-identical to the dense ascending loop.
template <int NPGL>
__global__ __launch_bounds__(256) void k_Bs(const float* __restrict__ adj,
                                            const float* __restrict__ u,
                                            float* __restrict__ t, float* __restrict__ dt,
                                            float* __restrict__ dis, int* __restrict__ cntG,
                                            int* __restrict__ nzcG, float* __restrict__ nzwG) {
  __shared__ int nzcS[4 * 64];
  __shared__ float nzwS[4 * 64];
  const int tid = threadIdx.x, w = tid >> 6, j = tid & 63;
  const int row = blockIdx.x * 4 + w;
  const int g = row / NPGL;
  const float* ug = u + (size_t)g * NPGL * 64;
  int* myc = nzcS + w * 64;
  float* myw = nzwS + w * 64;
  const unsigned long long below = (1ull << j) - 1ull;
  int base = 0;
  float ds = 0.f;
#pragma unroll
  for (int ch = 0; ch < NPGL / 64; ++ch) {
    float v = adj[(size_t)row * NPGL + ch * 64 + j];
    ds += v;
    unsigned long long m = __ballot(v != 0.f);
    int pos = base + __popcll(m & below);
    if (v != 0.f && pos < 64) { myc[pos] = ch * 64 + j; myw[pos] = v; }
    base += __popcll(m);
  }
  ds = wredsum(ds);
  const int cnt = base < 64 ? base : 64;
  const int cntP = (cnt + 3) & ~3;
  if (j < cntP - cnt) { myc[cnt + j] = 0; myw[cnt + j] = 0.f; }  // pad: +0*u[0] exact no-op
  const float disr = (ds > 0.f) ? (1.0f / sqrtf(ds)) : 0.f;
  float acc = 0.f;
  for (int k = 0; k < cntP; k += 4) {
    int4 c4 = *(const int4*)&myc[k];
    float4 w4 = *(const float4*)&myw[k];
    float ua = ug[(size_t)c4.x * 64 + j];
    float ub = ug[(size_t)c4.y * 64 + j];
    float uc = ug[(size_t)c4.z * 64 + j];
    float ud = ug[(size_t)c4.w * 64 + j];
    acc += w4.x * ua + w4.y * ub + w4.z * uc + w4.w * ud;
  }
  float v = bchain(acc);
  t[(size_t)row * 64 + j] = v;
  dt[(size_t)row * 64 + j] = disr * v;
  if (j == 0) { dis[row] = disr; cntG[row] = cntP; }
  if (j < cntP) { nzcG[(size_t)row * 64 + j] = myc[j]; nzwG[(size_t)row * 64 + j] = myw[j]; }
}

// ---- K4: sparse information score from stored CSR ----
template <int NPGL>
__global__ __launch_bounds__(256) void k_Cs(const int* __restrict__ cntG,
                                            const int* __restrict__ nzcG,
                                            const float* __restrict__ nzwG,
                                            const float* __restrict__ t,
                                            const float* __restrict__ dt,
                                            const float* __restrict__ dis,
                                            float* __restrict__ score) {
  const int tid = threadIdx.x, w = tid >> 6, j = tid & 63;
  const int row = blockIdx.x * 4 + w;
  const int g = row / NPGL;
  const float* dtg = dt + (size_t)g * NPGL * 64;
  const int cntP = cntG[row];
  float acc = 0.f;
  for (int k = 0; k < cntP; k += 4) {
    int4 c4 = *(const int4*)&nzcG[(size_t)row * 64 + k];
    float4 w4 = *(const float4*)&nzwG[(size_t)row * 64 + k];
    float ua = dtg[(size_t)c4.x * 64 + j];
    float ub = dtg[(size_t)c4.y * 64 + j];
    float uc = dtg[(size_t)c4.z * 64 + j];
    float ud = dtg[(size_t)c4.w * 64 + j];
    acc += w4.x * ua + w4.y * ub + w4.z * uc + w4.w * ud;
  }
  float d = fabsf(t[(size_t)row * 64 + j] - dis[row] * acc);
  d = wredsum(d);
  if (j == 0) score[row] = d;
}

// ---- dense HypAgg+HypAct (layer 2; adj2 ~55% dense) ----
template <int NPGL>
__global__ __launch_bounds__(256) void k_B(const float* __restrict__ adj,
                                           const float* __restrict__ u, float* __restrict__ t,
                                           float* __restrict__ dt, float* __restrict__ dis) {
  __shared__ float adjl[16 * NPGL];
  const int tid = threadIdx.x;
  const int w = tid >> 6, j = tid & 63;
  const int rowBase = blockIdx.x * 16;
  const int g = rowBase / NPGL;
  for (int f = tid; f < 16 * NPGL; f += 256) adjl[f] = adj[(size_t)rowBase * NPGL + f];
  __syncthreads();
  const float* ug = u + (size_t)g * NPGL * 64;
  float acc[4] = {0.f, 0.f, 0.f, 0.f};
  for (int c4 = 0; c4 < NPGL / 4; ++c4) {
    const int c = c4 * 4;
    float u0 = ug[(size_t)(c + 0) * 64 + j];
    float u1v = ug[(size_t)(c + 1) * 64 + j];
    float u2v = ug[(size_t)(c + 2) * 64 + j];
    float u3v = ug[(size_t)(c + 3) * 64 + j];
#pragma unroll
    for (int r = 0; r < 4; ++r) {
      float4 a4 = *(const float4*)&adjl[(w * 4 + r) * NPGL + c];
      acc[r] += a4.x * u0 + a4.y * u1v + a4.z * u2v + a4.w * u3v;
    }
  }
#pragma unroll
  for (int r = 0; r < 4; ++r) {
    const int lr = w * 4 + r;
    const int row = rowBase + lr;
    float ds = 0.f;
    for (int c = j; c < NPGL; c += 64) ds += adjl[lr * NPGL + c];
    ds = wredsum(ds);
    float disr = (ds > 0.f) ? (1.0f / sqrtf(ds)) : 0.f;
    float v = bchain(acc[r]);
    t[(size_t)row * 64 + j] = v;
    dt[(size_t)row * 64 + j] = disr * v;
    if (j == 0) dis[row] = disr;
  }
}

// ---- dense information score (layer 2) ----
template <int NPGL>
__global__ __launch_bounds__(256) void k_C(const float* __restrict__ adj,
                                           const float* __restrict__ t,
                                           const float* __restrict__ dt,
                                           const float* __restrict__ dis,
                                           float* __restrict__ score) {
  __shared__ float adjl[16 * NPGL];
  const int tid = threadIdx.x;
  const int w = tid >> 6, j = tid & 63;
  const int rowBase = blockIdx.x * 16;
  const int g = rowBase / NPGL;
  for (int f = tid; f < 16 * NPGL; f += 256) adjl[f] = adj[(size_t)rowBase * NPGL + f];
  __syncthreads();
  const float* dtg = dt + (size_t)g * NPGL * 64;
  float acc[4] = {0.f, 0.f, 0.f, 0.f};
  for (int c4 = 0; c4 < NPGL / 4; ++c4) {
    const int c = c4 * 4;
    float u0 = dtg[(size_t)(c + 0) * 64 + j];
    float u1v = dtg[(size_t)(c + 1) * 64 + j];
    float u2v = dtg[(size_t)(c + 2) * 64 + j];
    float u3v = dtg[(size_t)(c + 3) * 64 + j];
#pragma unroll
    for (int r = 0; r < 4; ++r) {
      float4 a4 = *(const float4*)&adjl[(w * 4 + r) * NPGL + c];
      acc[r] += a4.x * u0 + a4.y * u1v + a4.z * u2v + a4.w * u3v;
    }
  }
#pragma unroll
  for (int r = 0; r < 4; ++r) {
    const int row = rowBase + w * 4 + r;
    float d = fabsf(t[(size_t)row * 64 + j] - dis[row] * acc[r]);
    d = wredsum(d);
    if (j == 0) score[row] = d;
  }
}

// ---- per-graph top-k + xn gather + attention scalars + readout ----
template <int NPGL>
__global__ __launch_bounds__(256) void k_top(
    const float* __restrict__ score, const float* __restrict__ t,
    const float* __restrict__ att, int* __restrict__ selG,
    float* __restrict__ s1G, float* __restrict__ s2G,
    float* __restrict__ xnG, float* __restrict__ xr) {
  constexpr int K = NPGL / 2;
  const int g = blockIdx.x, tid = threadIdx.x, w = tid >> 6, j = tid & 63;
  __shared__ float scS[NPGL];
  __shared__ int selS[K];
  __shared__ float svalS[K];
  __shared__ float xnS[K * 64];
  for (int i = tid; i < NPGL; i += 256) scS[i] = score[(size_t)g * NPGL + i];
  __syncthreads();
  if (tid < NPGL) {
    float si = scS[tid];
    int rank = 0;
    for (int c = 0; c < NPGL; ++c) { float v = scS[c]; rank += (v > si) || (v == si && c < tid); }
    if (rank < K) { selS[rank] = tid; svalS[rank] = si; }
  }
  __syncthreads();
  const float a1 = att[j], a2 = att[64 + j];
  for (int i = w * (K / 4); i < (w + 1) * (K / 4); ++i) {
    int li = selS[i];
    float tv = tanhf(svalS[i]);
    float v = t[((size_t)g * NPGL + li) * 64 + j] * tv;
    xnS[i * 64 + j] = v;
    xnG[((size_t)g * K + i) * 64 + j] = v;
    float sa = wredsum(v * a1);
    float sb = wredsum(v * a2);
    if (j == 0) {
      s1G[(size_t)g * K + i] = sa;
      s2G[(size_t)g * K + i] = sb;
      selG[(size_t)g * K + i] = li;
    }
  }
  __syncthreads();
  if (tid < 64) {
    float mx = -1e30f, sm = 0.f;
    for (int r = 0; r < K; ++r) { float v = xnS[r * 64 + tid]; mx = fmaxf(mx, v); sm += v; }
    xr[(size_t)g * 128 + tid] = mx;
    xr[(size_t)g * 128 + 64 + tid] = sm * (1.0f / K);
  }
}

// ---- wide: structure-learning adj build + HypLinear achain (2 rows/wave) ----
template <int NPGL, int ADJB>
__global__ __launch_bounds__(256) void k_mid(
    const int* __restrict__ selG, const float* __restrict__ s1G,
    const float* __restrict__ s2G, const float* __restrict__ adjO,
    const float* __restrict__ xnG, const float* __restrict__ W,
    const float* __restrict__ b, float* __restrict__ adjN, float* __restrict__ uN) {
  constexpr int K = NPGL / 2;
  const int tid = threadIdx.x, w = tid >> 6, j = tid & 63;
  if (blockIdx.x < ADJB) {
    const int total = 32 * K * K;
    for (int idx = blockIdx.x * 256 + tid; idx < total; idx += ADJB * 256) {
      int g = idx / (K * K);
      int r = idx - g * K * K;
      int ii = r / K, jj = r - ii * K;
      float e = s1G[(size_t)g * K + ii] + s2G[(size_t)g * K + jj];
      adjN[idx] = fmaxf(e, 0.f) +
                  adjO[((size_t)g * NPGL + selG[(size_t)g * K + ii]) * NPGL +
                       selG[(size_t)g * K + jj]];
    }
    return;
  }
  __shared__ float SM[64 * 65];
  for (int idx = tid; idx < 4096; idx += 256) SM[(idx & 63) * 65 + (idx >> 6)] = W[idx];
  __syncthreads();
  float hbj, y2;
  biaschain(b, j, hbj, y2);
  const int rowBase = (blockIdx.x - ADJB) * 8;
#pragma unroll
  for (int rr = 0; rr < 2; ++rr) {
    const int r = rowBase + w * 2 + rr;
    float xrv = xnG[(size_t)r * 64 + j];
    float acc = 0.f;
#pragma unroll 8
    for (int t = 0; t < 64; ++t) acc += __shfl(xrv, t) * SM[t * 65 + j];
    uN[(size_t)r * 64 + j] = achain(xrv, acc, hbj, y2);
  }
}

// ---- final: B3 agg (all-LDS) + x3 readout + MLP + log_softmax ----
__global__ __launch_bounds__(1024) void k_fin(
    const float* __restrict__ adj3, const float* __restrict__ u3,
    const float* __restrict__ x1G, const float* __restrict__ x2G,
    const float* __restrict__ lw1, const float* __restrict__ lb1,
    const float* __restrict__ lw2, const float* __restrict__ lb2,
    const float* __restrict__ lw3, const float* __restrict__ lb3,
    float* __restrict__ out) {
  const int g = blockIdx.x, tid = threadIdx.x, w = tid >> 6, j = tid & 63;
  __shared__ float uS[64 * 64];
  __shared__ float t3S[64 * 64];
  __shared__ float rS[128], h1S[64], h2S[32], zS[8], x3S[128];
  for (int idx = tid; idx < 4096; idx += 1024) uS[idx] = u3[(size_t)g * 4096 + idx];
  __syncthreads();
#pragma unroll
  for (int ii = 0; ii < 4; ++ii) {
    int r = w * 4 + ii;
    float arow = adj3[(size_t)g * 4096 + r * 64 + j];
    float acc = 0.f;
#pragma unroll 8
    for (int c = 0; c < 64; ++c) acc += __shfl(arow, c) * uS[c * 64 + j];
    t3S[r * 64 + j] = bchain(acc);
  }
  __syncthreads();
  if (tid < 64) {
    float mx = -1e30f, sm = 0.f;
    for (int r = 0; r < 64; ++r) { float v = t3S[r * 64 + tid]; mx = fmaxf(mx, v); sm += v; }
    x3S[tid] = mx;
    x3S[64 + tid] = sm * (1.0f / 64.0f);
  }
  __syncthreads();
  if (tid < 128)
    rS[tid] = fmaxf(x1G[(size_t)g * 128 + tid], 0.f) + fmaxf(x2G[(size_t)g * 128 + tid], 0.f) +
              fmaxf(x3S[tid], 0.f);
  __syncthreads();
  if (tid < 64) {
    float a = lb1[tid];
    for (int t = 0; t < 128; ++t) a += rS[t] * lw1[(size_t)tid * 128 + t];
    h1S[tid] = fmaxf(a, 0.f);
  }
  __syncthreads();
  if (tid < 32) {
    float a = lb2[tid];
    for (int t = 0; t < 64; ++t) a += h1S[t] * lw2[(size_t)tid * 64 + t];
    h2S[tid] = fmaxf(a, 0.f);
  }
  __syncthreads();
  if (tid < 6) {
    float a = lb3[tid];
    for (int t = 0; t < 32; ++t) a += h2S[t] * lw3[(size_t)tid * 32 + t];
    zS[tid] = a;
  }
  __syncthreads();
  if (tid < 6) {
    float m = zS[0];
    for (int c = 1; c < 6; ++c) m = fmaxf(m, zS[c]);
    float se = 0.f;
    for (int c = 0; c < 6; ++c) se += expf(zS[c] - m);
    out[(size_t)g * 6 + tid] = zS[tid] - m - logf(se);
  }
}

extern "C" void kernel_launch(void* const* d_in, const int* in_sizes, int n_in,
                              void* d_out, int out_size, void* d_ws, size_t ws_size,
                              hipStream_t stream) {
  const float* x = (const float*)d_in[0];
  const int* ei = (const int*)d_in[1];
  const float* W1 = (const float*)d_in[2];
  const float* b1 = (const float*)d_in[3];
  const float* W2 = (const float*)d_in[4];
  const float* b2 = (const float*)d_in[5];
  const float* W3 = (const float*)d_in[6];
  const float* b3 = (const float*)d_in[7];
  const float* att1 = (const float*)d_in[8];
  const float* att2 = (const float*)d_in[9];
  const float* lw1 = (const float*)d_in[10];
  const float* lb1 = (const float*)d_in[11];
  const float* lw2 = (const float*)d_in[12];
  const float* lb2 = (const float*)d_in[13];
  const float* lw3 = (const float*)d_in[14];
  const float* lb3 = (const float*)d_in[15];
  float* out = (float*)d_out;
  const int nE = in_sizes[1] / 2;

  float* p = (float*)d_ws;
  float* srow = p;   p += 8192;
  float* adj1 = p;   p += (size_t)32 * 256 * 256;
  float* adj2 = p;   p += (size_t)32 * 128 * 128;
  float* adj3 = p;   p += (size_t)32 * 64 * 64;
  float* u1 = p;     p += (size_t)8192 * 64;
  float* t1 = p;     p += (size_t)8192 * 64;
  float* dt1 = p;    p += (size_t)8192 * 64;
  float* dis1 = p;   p += 8192;
  float* score1 = p; p += 8192;
  float* xn1 = p;    p += (size_t)4096 * 64;
  float* u2 = p;     p += (size_t)4096 * 64;
  float* t2 = p;     p += (size_t)4096 * 64;
  float* dt2 = p;    p += (size_t)4096 * 64;
  float* dis2 = p;   p += 4096;
  float* score2 = p; p += 4096;
  float* xn2 = p;    p += (size_t)2048 * 64;
  float* u3 = p;     p += (size_t)2048 * 64;
  float* s1a = p;    p += 4096;
  float* s2a = p;    p += 4096;
  float* s1b = p;    p += 2048;
  float* s2b = p;    p += 2048;
  float* x1G = p;    p += 32 * 128;
  float* x2G = p;    p += 32 * 128;
  float* nzw1 = p;   p += (size_t)8192 * 64;
  int* sel1 = (int*)p; p += 4096;
  int* sel2 = (int*)p; p += 2048;
  int* cnt1 = (int*)p; p += 8192;
  int* nzc1 = (int*)p; p += (size_t)8192 * 64;

  k_A1<<<1024, 256, 0, stream>>>(x, W1, b1, adj1, u1, srow);
  k_edges<<<128, 256, 0, stream>>>(ei, ei + nE, srow, adj1, nE);
  k_Bs<256><<<2048, 256, 0, stream>>>(adj1, u1, t1, dt1, dis1, cnt1, nzc1, nzw1);
  k_Cs<256><<<2048, 256, 0, stream>>>(cnt1, nzc1, nzw1, t1, dt1, dis1, score1);
  k_top<256><<<32, 256, 0, stream>>>(score1, t1, att1, sel1, s1a, s2a, xn1, x1G);
  k_mid<256, 256><<<768, 256, 0, stream>>>(sel1, s1a, s2a, adj1, xn1, W2, b2, adj2, u2);
  k_B<128><<<256, 256, 0, stream>>>(adj2, u2, t2, dt2, dis2);
  k_C<128><<<256, 256, 0, stream>>>(adj2, t2, dt2, dis2, score2);
  k_top<128><<<32, 256, 0, stream>>>(score2, t2, att2, sel2, s1b, s2b, xn2, x2G);
  k_mid<128, 64><<<320, 256, 0, stream>>>(sel2, s1b, s2b, adj2, xn2, W3, b3, adj3, u3);
  k_fin<<<32, 1024, 0, stream>>>(adj3, u3, x1G, x2G, lw1, lb1, lw2, lb2, lw3, lb3, out);
}